// Round 2
// baseline (46.535 us; speedup 1.0000x reference)
//
#include <hip/hip_runtime.h>
#include <hip/hip_bf16.h>

// TTT-M1 decode step (CS=1), B=128 H=32 HF=64.  All f32 in / f32 out.
//   z1[d]      = sum_f xb[f]*W[f][d] - xa[d]
//   g_new[f,d] = g[f,d] + xb[f]*z1[d]
//   w_new[f,d] = W[f,d] - coeff*g_new[f,d]
//   out[d]     = sum_f xc[f]*w_new[f,d]
// One block per (b,h). 256 threads; thread (c=tid&15, r=tid>>4) owns the
// 4x4 sub-tile rows 4r..4r+3 x cols 4c..4c+3 -> float4 global loads/stores
// (16B/lane coalesced).

namespace {

constexpr int HFD = 64;

union F4 { float4 v; float f[4]; };

__global__ __launch_bounds__(256, 4) void ttt_m1_decode(
    const float* __restrict__ W1i,
    const float* __restrict__ W1g,
    const float* __restrict__ XA,
    const float* __restrict__ XB,
    const float* __restrict__ XC,
    const float* __restrict__ coeff,
    float* __restrict__ oOut,   // [BH*64]
    float* __restrict__ oW1,    // [BH*4096]
    float* __restrict__ oG)     // [BH*4096]
{
    const int bh  = blockIdx.x;
    const int tid = threadIdx.x;
    const int c   = tid & 15;   // column group (4 cols)
    const int r   = tid >> 4;   // row group   (4 rows), 0..15
    const int d0  = c << 2;
    const int f0  = r << 2;

    const size_t mbase = (size_t)bh * (HFD * HFD);
    const float* Wi = W1i + mbase;
    const float* Wg = W1g + mbase;
    const float* xa = XA + bh * HFD;
    const float* xb = XB + bh * HFD;
    const float* xc = XC + bh * HFD;
    const float cf  = coeff[bh];

    __shared__ float redZ[16][HFD];
    __shared__ float redO[16][HFD];

    // --- load 4x4 tiles of W1_init / W1_grad as float4 rows ---
    F4 wi[4], wg[4];
#pragma unroll
    for (int j = 0; j < 4; ++j) {
        wi[j].v = *reinterpret_cast<const float4*>(Wi + (f0 + j) * HFD + d0);
        wg[j].v = *reinterpret_cast<const float4*>(Wg + (f0 + j) * HFD + d0);
    }
    float xbv[4], xcv[4];
#pragma unroll
    for (int j = 0; j < 4; ++j) { xbv[j] = xb[f0 + j]; xcv[j] = xc[f0 + j]; }
    F4 xav; xav.v = *reinterpret_cast<const float4*>(xa + d0);

    // --- partial z over our 4 rows, for our 4 columns ---
    F4 zp;
#pragma unroll
    for (int k = 0; k < 4; ++k)
        zp.f[k] = xbv[0]*wi[0].f[k] + xbv[1]*wi[1].f[k]
                + xbv[2]*wi[2].f[k] + xbv[3]*wi[3].f[k];
    *reinterpret_cast<float4*>(&redZ[r][d0]) = zp.v;
    __syncthreads();

    // --- full z1 for our 4 columns (sum of 16 row-group partials) ---
    F4 z1; z1.v = make_float4(0.f, 0.f, 0.f, 0.f);
#pragma unroll
    for (int rp = 0; rp < 16; ++rp) {
        F4 t; t.v = *reinterpret_cast<const float4*>(&redZ[rp][d0]);
#pragma unroll
        for (int k = 0; k < 4; ++k) z1.f[k] += t.f[k];
    }
#pragma unroll
    for (int k = 0; k < 4; ++k) z1.f[k] -= xav.f[k];

    // --- update grad & weights, write f32, accumulate out partial ---
    F4 op; op.v = make_float4(0.f, 0.f, 0.f, 0.f);
#pragma unroll
    for (int j = 0; j < 4; ++j) {
        F4 wout, gout;
#pragma unroll
        for (int k = 0; k < 4; ++k) {
            float gn = wg[j].f[k] + xbv[j] * z1.f[k];
            float wn = wi[j].f[k] - cf * gn;
            op.f[k] += xcv[j] * wn;
            gout.f[k] = gn;
            wout.f[k] = wn;
        }
        const size_t off = mbase + (size_t)(f0 + j) * HFD + d0;
        *reinterpret_cast<float4*>(oW1 + off) = wout.v;
        *reinterpret_cast<float4*>(oG  + off) = gout.v;
    }

    *reinterpret_cast<float4*>(&redO[r][d0]) = op.v;
    __syncthreads();

    // --- reduce out partials; lanes 0..63 write Out[d] ---
    if (tid < HFD) {
        float s = 0.f;
#pragma unroll
        for (int rp = 0; rp < 16; ++rp) s += redO[rp][tid];
        oOut[bh * HFD + tid] = s;
    }
}

} // namespace

extern "C" void kernel_launch(void* const* d_in, const int* in_sizes, int n_in,
                              void* d_out, int out_size, void* d_ws, size_t ws_size,
                              hipStream_t stream) {
    const float* W1i = (const float*)d_in[0];
    const float* W1g = (const float*)d_in[1];
    const float* XA  = (const float*)d_in[2];
    const float* XB  = (const float*)d_in[3];
    const float* XC  = (const float*)d_in[4];
    const float* cf  = (const float*)d_in[5];

    const int BH = in_sizes[0] / (64 * 64);  // 128*32 = 4096

    float* out  = (float*)d_out;
    float* oOut = out;                        // Out:        BH*64
    float* oW1  = out + (size_t)BH * 64;      // W1_init_new BH*4096
    float* oG   = oW1 + (size_t)BH * 4096;    // W1_grad_new BH*4096

    ttt_m1_decode<<<BH, 256, 0, stream>>>(W1i, W1g, XA, XB, XC, cf, oOut, oW1, oG);
}